// Round 5
// baseline (1065.749 us; speedup 1.0000x reference)
//
#include <hip/hip_runtime.h>
#include <math.h>

#define NFEAT 65536
#define KS1   32        // k slices (2048 each)
#define NTILE 32        // max 64-row group-uniform tiles

// ---- ws layout (float offsets) — harness-proven round-1/3/4 layout ----
#define WS_Z     0          // [1024][64] atomic accum mu|ls   (memset)
#define WS_T     65536      // [1024][32] atomic accum T       (memset)
#define WS_SS    98304      // [1024] sum(flat^2)              (memset)
#define WS_SCAL  99328      // [2] freq_loss, roi_loss         (memset; pad to 99392)
#define WS_FSP   99392      // [16][32][64] softplus freq
#define WS_R1SP  132160     // [16][32][32]
#define WS_R2SP  148544     // [16][32][32]
#define WS_G     164928     // [16][32][32] Gram
#define WS_LOSSB 181312     // [1024]
#define WS_SORTI 182336     // int region: order[2048], tg[32], tb[32], tc[32]
#define WS_FT    184832     // (unused this round)
#define WS_R1T   217600     // (unused this round)
#define WS_WP    233984     // bf16[8192 kg][64 col][8] fragment-packed W1|W2 (8 MB)
// end: 233984 + 2097152 = 2331136 floats = 9.33 MB

typedef __bf16 bf16x8 __attribute__((ext_vector_type(8)));
typedef float  floatx4 __attribute__((ext_vector_type(4)));

__device__ __forceinline__ float softplusf(float x) {
    return fmaxf(x, 0.f) + log1pf(expf(-fabsf(x)));
}

__device__ __forceinline__ void glds16(const void* g, void* l) {
    __builtin_amdgcn_global_load_lds(
        (const __attribute__((address_space(1))) unsigned int*)g,
        (__attribute__((address_space(3))) unsigned int*)l, 16, 0, 0);
}

// ---- K0a combined: softplus factors | W prepack | sort ----
__global__ __launch_bounds__(256) void k0a(const float* __restrict__ ff,
                                           const float* __restrict__ r1,
                                           const float* __restrict__ r2,
                                           const float* __restrict__ W1,
                                           const float* __restrict__ W2,
                                           const int* __restrict__ groups,
                                           float* __restrict__ ws) {
    const int bid = blockIdx.x, t = threadIdx.x;
    __shared__ int cnt[16], pos[16];
    if (bid < 256) {
        int i = bid * 256 + t;
        if (i < 32768) {
            ws[WS_FSP + i] = softplusf(ff[i]);
        } else if (i < 49152) {
            int ii = i - 32768;
            ws[WS_R1SP + ii] = softplusf(r1[ii]);
        } else {
            int ii = i - 49152;
            ws[WS_R2SP + ii] = softplusf(r2[ii]);
        }
    } else if (bid < 2304) {
        // W prepack: fragment (kg, col) = bf16 W[(kg*8+j)][col], col 0..31->W1, 32..63->W2
        int e = (bid - 256) * 256 + t;          // 0 .. 524287
        int kg = e >> 6, col = e & 63;
        const float* Wsrc = (col < 32 ? W1 : W2) + (size_t)kg * 256 + (col & 31);
        bf16x8 o;
        #pragma unroll
        for (int j = 0; j < 8; j++) o[j] = (__bf16)Wsrc[j * 32];
        *(bf16x8*)((__bf16*)(ws + WS_WP) + (size_t)e * 8) = o;
    } else {
        // ---- sort batches by group into 64-row tiles ----
        int* order = (int*)(ws + WS_SORTI);
        int* tg = order + 2048; int* tb = order + 2080; int* tc = order + 2112;
        if (t < 16) cnt[t] = 0;
        __syncthreads();
        for (int i = t; i < 1024; i += 256) atomicAdd(&cnt[groups[i]], 1);
        __syncthreads();
        if (t == 0) {
            int tt = 0, base = 0;
            for (int g = 0; g < 16; g++) {
                pos[g] = base;
                int c = cnt[g];
                int nt = (c + 63) >> 6;
                for (int j = 0; j < nt; j++) {
                    tg[tt] = g; tb[tt] = base + j * 64;
                    int rem = c - j * 64;
                    tc[tt] = rem < 64 ? rem : 64;
                    tt++;
                }
                base += c;
            }
            for (; tt < NTILE; tt++) { tg[tt] = 0; tb[tt] = 0; tc[tt] = 0; }
        }
        __syncthreads();
        for (int i = t; i < 1024; i += 256) {
            int s = atomicAdd(&pos[groups[i]], 1);
            order[s] = i;
        }
        for (int i = 1024 + t; i < 2048; i += 256) order[i] = 0;
    }
}

// ---- K0b combined: variance losses | per-group Gram ----
__global__ __launch_bounds__(256) void k0b(float* __restrict__ ws) {
    __shared__ float red[256];
    __shared__ float Fg[2048], R1g[1024], R2g[1024];
    const int bid = blockIdx.x, t = threadIdx.x;
    if (bid < 12) {
        int gid = bid * 256 + t;
        float contrib = 0.f;
        if (gid < 2048) {
            const float* F = ws + WS_FSP + gid;
            float sx = 0.f, sx2 = 0.f;
            #pragma unroll
            for (int g = 0; g < 16; g++) { float x = F[g * 2048]; sx += x; sx2 += x * x; }
            contrib = (sx2 - sx * sx * (1.f / 16.f)) * (1.f / 15.f) * (1.f / 64.f);
        } else {
            int p = gid - 2048;
            const float* A = ws + WS_R1SP + p;
            const float* B = ws + WS_R2SP + p;
            float sx = 0.f, sx2 = 0.f, tx = 0.f, tx2 = 0.f;
            #pragma unroll
            for (int g = 0; g < 16; g++) {
                float x = A[g * 1024]; sx += x; sx2 += x * x;
                float y = B[g * 1024]; tx += y; tx2 += y * y;
            }
            contrib = ((sx2 - sx * sx * (1.f / 16.f)) + (tx2 - tx * tx * (1.f / 16.f)))
                      * (1.f / 15.f) * (1.f / 32.f);
        }
        red[t] = contrib;
        __syncthreads();
        for (int o = 128; o > 0; o >>= 1) {
            if (t < o) red[t] += red[t + o];
            __syncthreads();
        }
        if (t == 0) atomicAdd(ws + WS_SCAL + (bid < 8 ? 0 : 1), red[0]);
    } else {
        int g = bid - 12;
        for (int i = t; i < 2048; i += 256) Fg[i] = ws[WS_FSP + g * 2048 + i];
        for (int i = t; i < 1024; i += 256) {
            R1g[i] = ws[WS_R1SP + g * 1024 + i];
            R2g[i] = ws[WS_R2SP + g * 1024 + i];
        }
        __syncthreads();
        for (int p = t; p < 1024; p += 256) {
            int z1 = p >> 5, z2 = p & 31;
            float dF = 0.f;
            for (int f = 0; f < 64; f++) dF += Fg[z1 * 64 + f] * Fg[z2 * 64 + f];
            float d1 = 0.f, d2 = 0.f;
            for (int r = 0; r < 32; r++) {
                d1 += R1g[z1 * 32 + r] * R1g[z2 * 32 + r];
                d2 += R2g[z1 * 32 + r] * R2g[z2 * 32 + r];
            }
            ws[WS_G + g * 1024 + p] = dF * d1 * d2;
        }
    }
}

// ---- fused: GEMM [64 x 2048] x [2048 x 96] per block; N = W1(32)|W2(32)|Kg(32)
//      K-chunk=128 (16 iters), register-double-buffered A, glds16 W staging,
//      counted-vmcnt barrier. NEW: Kg built per-lane in REGISTERS (no Kg LDS),
//      Bsm = W only, dense 32 KB -> 4 blocks/CU.
__global__ __launch_bounds__(256, 4) void k_fused(const float* __restrict__ feat,
                                                  float* __restrict__ wsf) {
    const int rt = blockIdx.x, ks = blockIdx.y;
    const int* order = (const int*)(wsf + WS_SORTI);
    const int tcnt = order[2112 + rt];
    if (tcnt == 0) return;
    const int g     = order[2048 + rt];
    const int tbase = order[2080 + rt];

    __shared__ __bf16 Bsm[2][16][512];   // [buf][kg][col*8] W fragments; 32 KB
    const int tid = threadIdx.x;
    const int w = tid >> 6, lane = tid & 63;
    const int fn = lane & 15, q4 = lane >> 4;
    const size_t kbase = (size_t)ks * 2048;

    const int rowit = w * 16 + fn;
    const int bA = order[tbase + rowit];
    const float* fp = feat + (size_t)bA * NFEAT + kbase + q4 * 8;

    // ---- per-lane Kg ingredients (z = fn for b4, fn+16 for b5) ----
    // k = ks*2048 + cc*128 + kg*8 + j ; kg = kq*4+q4
    //   f  = ks*2 + (cc>>3)            -> fva/fvb (float2, selected by cc bit 3)
    //   r1 = (cc&7)*4 + kq             -> r1a/r1b float4 per cc, component kq
    //   r2 = q4*8 + j                  -> r2a/r2b 8 floats, kernel-constant
    float2 fva = *(const float2*)(wsf + WS_FSP + g * 2048 + fn * 64 + ks * 2);
    float2 fvb = *(const float2*)(wsf + WS_FSP + g * 2048 + (fn + 16) * 64 + ks * 2);
    float4 r2a0 = *(const float4*)(wsf + WS_R2SP + g * 1024 + fn * 32 + q4 * 8);
    float4 r2a1 = *(const float4*)(wsf + WS_R2SP + g * 1024 + fn * 32 + q4 * 8 + 4);
    float4 r2b0 = *(const float4*)(wsf + WS_R2SP + g * 1024 + (fn + 16) * 32 + q4 * 8);
    float4 r2b1 = *(const float4*)(wsf + WS_R2SP + g * 1024 + (fn + 16) * 32 + q4 * 8 + 4);
    const float* R1a = wsf + WS_R1SP + g * 1024 + fn * 32;          // + (cc&7)*4
    const float* R1b = wsf + WS_R1SP + g * 1024 + (fn + 16) * 32;

    const __bf16* wp = (const __bf16*)(wsf + WS_WP);
    const size_t kgb = (size_t)ks * 256;    // kg-block base; + cc*16 + (w*4+p)

    float4 rA[2][8];
    float4 r1a[2], r1b[2];

    // ---- prologue: stage chunk 0 ----
    #pragma unroll
    for (int p = 0; p < 4; p++)
        glds16(wp + ((kgb + (size_t)(w * 4 + p)) * 64 + (size_t)lane) * 8,
               &Bsm[0][w * 4 + p][0]);
    #pragma unroll
    for (int kq = 0; kq < 4; kq++) {
        rA[0][kq * 2]     = *(const float4*)(fp + kq * 32);
        rA[0][kq * 2 + 1] = *(const float4*)(fp + kq * 32 + 4);
    }
    r1a[0] = *(const float4*)(R1a);
    r1b[0] = *(const float4*)(R1b);
    __syncthreads();   // full drain once (covers glds chunk 0)

    floatx4 acc0 = {0,0,0,0}, acc1 = {0,0,0,0}, acc2 = {0,0,0,0};
    floatx4 acc3 = {0,0,0,0}, acc4 = {0,0,0,0}, acc5 = {0,0,0,0};
    float ssl = 0.f;

    #pragma unroll 2
    for (int cc = 0; cc < 16; cc++) {
        const int cur = cc & 1, nxt = cur ^ 1;
        if (cc < 15) {
            // VMEM issue order pinned: [4 glds][8 A][2 r1]
            #pragma unroll
            for (int p = 0; p < 4; p++)
                glds16(wp + ((kgb + (size_t)((cc + 1) * 16 + w * 4 + p)) * 64 + (size_t)lane) * 8,
                       &Bsm[nxt][w * 4 + p][0]);
            __builtin_amdgcn_sched_barrier(0);
            const float* fpn = fp + (cc + 1) * 128;
            #pragma unroll
            for (int kq = 0; kq < 4; kq++) {
                rA[nxt][kq * 2]     = *(const float4*)(fpn + kq * 32);
                rA[nxt][kq * 2 + 1] = *(const float4*)(fpn + kq * 32 + 4);
            }
            __builtin_amdgcn_sched_barrier(0);
            r1a[nxt] = *(const float4*)(R1a + ((cc + 1) & 7) * 4);
            r1b[nxt] = *(const float4*)(R1b + ((cc + 1) & 7) * 4);
            __builtin_amdgcn_sched_barrier(0);
        }
        const float fA = (cc & 8) ? fva.y : fva.x;
        const float fB = (cc & 8) ? fvb.y : fvb.x;
        const float r1av[4] = {r1a[cur].x, r1a[cur].y, r1a[cur].z, r1a[cur].w};
        const float r1bv[4] = {r1b[cur].x, r1b[cur].y, r1b[cur].z, r1b[cur].w};
        // compute chunk cc
        __builtin_amdgcn_s_setprio(1);
        #pragma unroll
        for (int kq = 0; kq < 4; kq++) {
            float4 lo = rA[cur][kq * 2], hi = rA[cur][kq * 2 + 1];
            ssl += lo.x*lo.x + lo.y*lo.y + lo.z*lo.z + lo.w*lo.w
                 + hi.x*hi.x + hi.y*hi.y + hi.z*hi.z + hi.w*hi.w;
            bf16x8 af;
            af[0]=(__bf16)lo.x; af[1]=(__bf16)lo.y; af[2]=(__bf16)lo.z; af[3]=(__bf16)lo.w;
            af[4]=(__bf16)hi.x; af[5]=(__bf16)hi.y; af[6]=(__bf16)hi.z; af[7]=(__bf16)hi.w;
            const __bf16* bb = &Bsm[cur][kq * 4 + q4][fn * 8];
            bf16x8 b0 = *(const bf16x8*)(bb);
            bf16x8 b1 = *(const bf16x8*)(bb + 128);
            bf16x8 b2 = *(const bf16x8*)(bb + 256);
            bf16x8 b3 = *(const bf16x8*)(bb + 384);
            // Kg fragments in registers (bit-identical math to the LDS-staged path)
            float cfA = fA * r1av[kq];
            float cfB = fB * r1bv[kq];
            bf16x8 b4, b5;
            b4[0]=(__bf16)(cfA*r2a0.x); b4[1]=(__bf16)(cfA*r2a0.y);
            b4[2]=(__bf16)(cfA*r2a0.z); b4[3]=(__bf16)(cfA*r2a0.w);
            b4[4]=(__bf16)(cfA*r2a1.x); b4[5]=(__bf16)(cfA*r2a1.y);
            b4[6]=(__bf16)(cfA*r2a1.z); b4[7]=(__bf16)(cfA*r2a1.w);
            b5[0]=(__bf16)(cfB*r2b0.x); b5[1]=(__bf16)(cfB*r2b0.y);
            b5[2]=(__bf16)(cfB*r2b0.z); b5[3]=(__bf16)(cfB*r2b0.w);
            b5[4]=(__bf16)(cfB*r2b1.x); b5[5]=(__bf16)(cfB*r2b1.y);
            b5[6]=(__bf16)(cfB*r2b1.z); b5[7]=(__bf16)(cfB*r2b1.w);
            acc0 = __builtin_amdgcn_mfma_f32_16x16x32_bf16(af, b0, acc0, 0, 0, 0);
            acc1 = __builtin_amdgcn_mfma_f32_16x16x32_bf16(af, b1, acc1, 0, 0, 0);
            acc2 = __builtin_amdgcn_mfma_f32_16x16x32_bf16(af, b2, acc2, 0, 0, 0);
            acc3 = __builtin_amdgcn_mfma_f32_16x16x32_bf16(af, b3, acc3, 0, 0, 0);
            acc4 = __builtin_amdgcn_mfma_f32_16x16x32_bf16(af, b4, acc4, 0, 0, 0);
            acc5 = __builtin_amdgcn_mfma_f32_16x16x32_bf16(af, b5, acc5, 0, 0, 0);
        }
        __builtin_amdgcn_s_setprio(0);
        if (cc < 15) {
            // drain ONLY the 4 glds (oldest); 8 A + 2 r1 stay in flight across barrier
            asm volatile("s_waitcnt vmcnt(10) lgkmcnt(0)" ::: "memory");
            __builtin_amdgcn_sched_barrier(0);
            __builtin_amdgcn_s_barrier();
        }
    }

    // ---- epilogue (proven atomics) ----
    float ssv = ssl + __shfl_xor(ssl, 16, 64);
    ssv += __shfl_xor(ssv, 32, 64);
    if (q4 == 0 && rowit < tcnt) atomicAdd(wsf + WS_SS + bA, ssv);

    #pragma unroll
    for (int r = 0; r < 4; r++) {
        int rit = w * 16 + q4 * 4 + r;
        if (rit < tcnt) {
            int b = order[tbase + rit];
            atomicAdd(wsf + WS_Z + b * 64 +  0 + fn, acc0[r]);
            atomicAdd(wsf + WS_Z + b * 64 + 16 + fn, acc1[r]);
            atomicAdd(wsf + WS_Z + b * 64 + 32 + fn, acc2[r]);
            atomicAdd(wsf + WS_Z + b * 64 + 48 + fn, acc3[r]);
            atomicAdd(wsf + WS_T + b * 32 +  0 + fn, acc4[r]);
            atomicAdd(wsf + WS_T + b * 32 + 16 + fn, acc5[r]);
        }
    }
}

// ---- K3: per-batch epilogue ----
__global__ __launch_bounds__(64) void k3_batch(const float* __restrict__ W1,
                                               const float* __restrict__ W2,
                                               const float* __restrict__ b1,
                                               const float* __restrict__ b2,
                                               const float* __restrict__ gemb,
                                               const float* __restrict__ noise,
                                               const float* __restrict__ linW,
                                               const float* __restrict__ linb,
                                               const float* __restrict__ lbias,
                                               const int* __restrict__ groups,
                                               const int* __restrict__ labels,
                                               const float* __restrict__ weights,
                                               float* __restrict__ ws) {
    const int b = blockIdx.x;
    const int t = threadIdx.x;
    const int g = groups[b];
    float sum = ws[WS_Z + b * 64 + t];

    __shared__ float s_mu[32], s_sig[32], s_zs0[32], s_zs[32], s_P[32], s_red[96];
    float ge0 = gemb[g * 2], ge1 = gemb[g * 2 + 1];
    if (t < 32) {
        s_mu[t] = sum + ge0 * W1[(size_t)65536 * 32 + t] + ge1 * W1[(size_t)65537 * 32 + t] + b1[t];
    } else {
        int c = t - 32;
        float ls = sum + ge0 * W2[(size_t)65536 * 32 + c] + ge1 * W2[(size_t)65537 * 32 + c] + b2[c];
        s_sig[c] = 1e-6f + expf(ls);
    }
    __syncthreads();
    if (t < 32) s_zs0[t] = s_mu[t] + s_sig[t] * noise[b * 32 + t];
    __syncthreads();
    if (t < 32) {
        float d = linb[t];
        for (int i = 0; i < 32; i++) d = fmaf(s_zs0[i], linW[i * 32 + t], d);
        s_zs[t] = d;
        s_P[t] = softplusf(d);
    }
    __syncthreads();
    if (t < 32) {
        float mu = s_mu[t], sg = s_sig[t];
        float kld = -logf(sg) + 0.5f * (sg * sg + mu * mu - 1.f);
        float pt = s_P[t] * ws[WS_T + b * 32 + t];
        const float* Grow = ws + WS_G + g * 1024 + t * 32;
        float gd = 0.f;
        for (int j = 0; j < 32; j++) gd = fmaf(Grow[j], s_P[j], gd);
        s_red[t] = kld; s_red[32 + t] = pt; s_red[64 + t] = s_P[t] * gd;
    }
    __syncthreads();
    if (t == 0) {
        float kld = 0.f, pt = 0.f, pgp = 0.f;
        for (int i = 0; i < 32; i++) { kld += s_red[i]; pt += s_red[32 + i]; pgp += s_red[64 + i]; }
        float rec = (ws[WS_SS + b] - 2.f * pt + pgp) * (1.f / 65536.f);
        float l0 = s_zs[0] + lbias[0], l1 = s_zs[1] + lbias[1];
        float l2 = s_zs[2] + lbias[2], l3 = 1.f + lbias[3];
        float m = fmaxf(fmaxf(l0, l1), fmaxf(l2, l3));
        float lse = m + logf(expf(l0 - m) + expf(l1 - m) + expf(l2 - m) + expf(l3 - m));
        int lb = labels[b];
        float ll = ((lb == 0) ? l0 : (lb == 1) ? l1 : (lb == 2) ? l2 : l3) - lse;
        ws[WS_LOSSB + b] = rec - weights[b] * ll + kld;
    }
}

// ---- K4: final scalar ----
__global__ __launch_bounds__(256) void k4_final(const float* __restrict__ ws, float* __restrict__ out) {
    __shared__ float red[256];
    int t = threadIdx.x;
    float s = 0.f;
    for (int i = t; i < 1024; i += 256) s += ws[WS_LOSSB + i];
    red[t] = s;
    __syncthreads();
    for (int o = 128; o > 0; o >>= 1) {
        if (t < o) red[t] += red[t + o];
        __syncthreads();
    }
    if (t == 0) out[0] = red[0] * (1.f / 1024.f) + ws[WS_SCAL] + ws[WS_SCAL + 1];
}

extern "C" void kernel_launch(void* const* d_in, const int* in_sizes, int n_in,
                              void* d_out, int out_size, void* d_ws, size_t ws_size,
                              hipStream_t stream) {
    const float* feat    = (const float*)d_in[0];
    const int*   labels  = (const int*)d_in[1];
    const int*   groups  = (const int*)d_in[2];
    const float* weights = (const float*)d_in[3];
    const float* noise   = (const float*)d_in[4];
    const float* gemb    = (const float*)d_in[5];
    const float* W1      = (const float*)d_in[6];
    const float* b1      = (const float*)d_in[7];
    const float* W2      = (const float*)d_in[8];
    const float* b2      = (const float*)d_in[9];
    const float* ff      = (const float*)d_in[10];
    const float* r1f     = (const float*)d_in[11];
    const float* r2f     = (const float*)d_in[12];
    const float* linW    = (const float*)d_in[13];
    const float* linb    = (const float*)d_in[14];
    const float* lbias   = (const float*)d_in[15];
    float* ws = (float*)d_ws;
    float* out = (float*)d_out;

    // zero Z/T/SS/SCAL accumulators
    hipMemsetAsync(ws, 0, 99392 * sizeof(float), stream);

    // factors | W prepack | sort — one launch
    k0a<<<2305, 256, 0, stream>>>(ff, r1f, r2f, W1, W2, groups, ws);
    // variance losses | Gram — one launch
    k0b<<<28, 256, 0, stream>>>(ws);
    k_fused<<<dim3(NTILE, KS1), 256, 0, stream>>>(feat, ws);
    k3_batch<<<1024, 64, 0, stream>>>(W1, W2, b1, b2, gemb, noise, linW, linb, lbias,
                                      groups, labels, weights, ws);
    k4_final<<<1, 256, 0, stream>>>(ws, out);
}